// Round 7
// baseline (399.079 us; speedup 1.0000x reference)
//
#include <hip/hip_runtime.h>
#include <math.h>

#define N_NODES 100000
#define N_EDGES 1600000
#define DIM 32
#define N_GROUPS 64
#define BN_EPS 1e-5f

#define BIN_NODES 128
#define NBINS ((N_NODES + BIN_NODES - 1) / BIN_NODES)   // 782
#define EPB_HIST 8192
#define HIST_BLOCKS ((N_EDGES + EPB_HIST - 1) / EPB_HIST)  // 196

// ---- monotone float<->uint encoding for atomic max on floats ----
__device__ __forceinline__ unsigned enc_f32(float f) {
    unsigned u = __float_as_uint(f);
    return (u & 0x80000000u) ? ~u : (u | 0x80000000u);
}
__device__ __forceinline__ float dec_f32(unsigned u) {
    return (u & 0x80000000u) ? __uint_as_float(u & 0x7FFFFFFFu) : __uint_as_float(~u);
}
// fp32 -> bf16 bits (RNE)
__device__ __forceinline__ unsigned short f2bf(float f) {
    unsigned u = __float_as_uint(f);
    u += 0x7FFFu + ((u >> 16) & 1u);
    return (unsigned short)(u >> 16);
}

// Fold BN into weights
__global__ void fold_kernel(const float* __restrict__ lin_W, const float* __restrict__ lin_b,
                            const float* __restrict__ lin_gamma, const float* __restrict__ lin_beta,
                            const float* __restrict__ lin_mean, const float* __restrict__ lin_var,
                            const float* __restrict__ conv_W, const float* __restrict__ conv_b,
                            const float* __restrict__ conv_gamma, const float* __restrict__ conv_beta,
                            const float* __restrict__ conv_mean, const float* __restrict__ conv_var,
                            float* __restrict__ Wf, float* __restrict__ shf)
{
    int l = blockIdx.x;      // 0..2 = lin, 3..4 = conv
    int t = threadIdx.x;
    const float *W, *b, *gm, *bt, *mn, *vr;
    if (l < 3) {
        W = lin_W + l * DIM * DIM; b = lin_b + l * DIM; gm = lin_gamma + l * DIM;
        bt = lin_beta + l * DIM;   mn = lin_mean + l * DIM; vr = lin_var + l * DIM;
    } else {
        int c = l - 3;
        W = conv_W + c * DIM * DIM; b = conv_b + c * DIM; gm = conv_gamma + c * DIM;
        bt = conv_beta + c * DIM;   mn = conv_mean + c * DIM; vr = conv_var + c * DIM;
    }
    int j = t & (DIM - 1);
    float scale = gm[j] / sqrtf(vr[j] + BN_EPS);
    Wf[l * DIM * DIM + t] = W[t] * scale;
    if (t < DIM) shf[l * DIM + t] = (b[t] - mn[t]) * scale + bt[t];
}

// x (fp32) -> xb (bf16 bits), 4 elems/thread
__global__ __launch_bounds__(256) void convert_kernel(const float* __restrict__ x,
                                                      unsigned short* __restrict__ xb) {
    int i = blockIdx.x * 256 + threadIdx.x;          // grid exact: N*DIM/4/256
    float4 v = ((const float4*)x)[i];
    uint2 o;
    o.x = (unsigned)f2bf(v.x) | ((unsigned)f2bf(v.y) << 16);
    o.y = (unsigned)f2bf(v.z) | ((unsigned)f2bf(v.w) << 16);
    ((uint2*)xb)[i] = o;
}

// ================= bin-grouped edge build (cheap, proven) =================
__global__ __launch_bounds__(256) void binhist_kernel(const int* __restrict__ dst,
                                                      int* __restrict__ bincnt) {
    __shared__ int cnt[NBINS];
    int t = threadIdx.x;
    for (int b = t; b < NBINS; b += 256) cnt[b] = 0;
    __syncthreads();
    int base = blockIdx.x * EPB_HIST;
    for (int i = 0; i < EPB_HIST / 256; ++i) {
        int e = base + i * 256 + t;
        if (e < N_EDGES) atomicAdd(&cnt[dst[e] >> 7], 1);
    }
    __syncthreads();
    for (int b = t; b < NBINS; b += 256)
        if (cnt[b] > 0) atomicAdd(&bincnt[b], cnt[b]);
}

__global__ __launch_bounds__(1024) void binscan_kernel(const int* __restrict__ bincnt,
                                                       int* __restrict__ binoff,
                                                       int* __restrict__ bincur) {
    __shared__ int s[1024];
    int t = threadIdx.x;
    int c = (t < NBINS) ? bincnt[t] : 0;
    s[t] = c;
    __syncthreads();
    for (int off = 1; off < 1024; off <<= 1) {
        int u = (t >= off) ? s[t - off] : 0;
        __syncthreads();
        s[t] += u;
        __syncthreads();
    }
    if (t < NBINS) { binoff[t] = s[t] - c; bincur[t] = s[t] - c; }
    if (t == 0) binoff[NBINS] = N_EDGES;
}

__global__ __launch_bounds__(256) void binscatter_kernel(const int* __restrict__ src,
                                                         const int* __restrict__ dst,
                                                         int* __restrict__ bincur,
                                                         unsigned* __restrict__ binbuf) {
    __shared__ int cnt[NBINS];
    __shared__ int pos[NBINS];
    int t = threadIdx.x;
    for (int b = t; b < NBINS; b += 256) cnt[b] = 0;
    __syncthreads();
    int base = blockIdx.x * EPB_HIST;
    for (int i = 0; i < EPB_HIST / 256; ++i) {
        int e = base + i * 256 + t;
        if (e < N_EDGES) atomicAdd(&cnt[dst[e] >> 7], 1);
    }
    __syncthreads();
    for (int b = t; b < NBINS; b += 256) {
        int c = cnt[b];
        pos[b] = (c > 0) ? atomicAdd(&bincur[b], c) : 0;
    }
    __syncthreads();
    for (int i = 0; i < EPB_HIST / 256; ++i) {
        int e = base + i * 256 + t;
        if (e < N_EDGES) {
            int d = dst[e];
            int bin = d >> 7;
            int p = atomicAdd(&pos[bin], 1);
            binbuf[p] = ((unsigned)(d & 127) << 17) | (unsigned)src[e];
        }
    }
}

// counting sort within bin -> exact per-node CSR
__global__ __launch_bounds__(256) void binsort_kernel(const unsigned* __restrict__ binbuf,
                                                      const int* __restrict__ binoff,
                                                      int* __restrict__ esrc,
                                                      int* __restrict__ nodeptr) {
    __shared__ int cnt[BIN_NODES];
    __shared__ int sc[BIN_NODES];
    int t = threadIdx.x;
    int bin = blockIdx.x;
    int beg = binoff[bin], end = binoff[bin + 1];
    if (t < BIN_NODES) cnt[t] = 0;
    __syncthreads();
    for (int e = beg + t; e < end; e += 256)
        atomicAdd(&cnt[binbuf[e] >> 17], 1);
    __syncthreads();
    int v = (t < BIN_NODES) ? cnt[t] : 0;
    if (t < BIN_NODES) sc[t] = v;
    __syncthreads();
    for (int off = 1; off < BIN_NODES; off <<= 1) {
        int u = (t < BIN_NODES && t >= off) ? sc[t - off] : 0;
        __syncthreads();
        if (t < BIN_NODES) sc[t] += u;
        __syncthreads();
    }
    if (t < BIN_NODES) {
        int excl = sc[t] - v;
        cnt[t] = excl;
        nodeptr[bin * BIN_NODES + t] = beg + excl;
    }
    __syncthreads();
    for (int e = beg + t; e < end; e += 256) {
        unsigned pe = binbuf[e];
        int dl = (int)(pe >> 17);
        int p = atomicAdd(&cnt[dl], 1);
        esrc[beg + p] = (int)(pe & 0x1FFFFu);
    }
}

// ===== fused gather(bf16) + conv-MLP: x'[i] = elu((x[i]+sum_j x[j]) @ Wc + shc) =====
// One wave per node. Gathers read bf16 rows (64 B) to shrink L2 working set;
// self-row and MLP in fp32. Also emits bf16 copy of x' for the next layer's gather.
__global__ __launch_bounds__(256) void gatherconv_kernel(
        const float* __restrict__ x,              // fp32 layer input
        const unsigned short* __restrict__ xb,    // bf16 bits of same
        const int* __restrict__ esrc,
        const int* __restrict__ nodeptr,
        const float* __restrict__ Wc, const float* __restrict__ shc,
        float* __restrict__ xnext,
        unsigned short* __restrict__ xnextb)
{
    __shared__ float Wb[DIM * DIM];
    __shared__ float shb[DIM];
    __shared__ float h[4][DIM];
    int t = threadIdx.x;
    for (int i = t; i < DIM * DIM; i += 256) Wb[i] = Wc[i];
    if (t < DIM) shb[t] = shc[t];
    __syncthreads();

    int wv = t >> 6;
    int lane = t & 63;
    int node = blockIdx.x * 4 + wv;          // grid exact: N/4
    int slot = lane >> 3;                    // 8 edge slots
    int c4 = (lane & 7) * 4;                 // 4-col chunk

    int beg = nodeptr[node];
    int end = nodeptr[node + 1];
    float4 acc = make_float4(0.f, 0.f, 0.f, 0.f);
    for (int e = beg + slot; e < end; e += 8) {
        int s = esrc[e];
        uint2 u = *(const uint2*)(xb + (size_t)s * DIM + c4);   // 4 bf16 = 8 B
        acc.x += __uint_as_float(u.x << 16);
        acc.y += __uint_as_float(u.x & 0xFFFF0000u);
        acc.z += __uint_as_float(u.y << 16);
        acc.w += __uint_as_float(u.y & 0xFFFF0000u);
    }
#pragma unroll
    for (int off = 8; off < 64; off <<= 1) {
        acc.x += __shfl_xor(acc.x, off, 64);
        acc.y += __shfl_xor(acc.y, off, 64);
        acc.z += __shfl_xor(acc.z, off, 64);
        acc.w += __shfl_xor(acc.w, off, 64);
    }
    if (slot == 0) {
        const float4 xv = *(const float4*)(x + (size_t)node * DIM + c4);
        float4 r = make_float4(acc.x + xv.x, acc.y + xv.y, acc.z + xv.z, acc.w + xv.w);
        *(float4*)(&h[wv][c4]) = r;          // same-wave LDS; no block barrier needed
    }
    // conv MLP: halves split k, fold with shfl_xor(32)
    int col = lane & 31;
    int half = lane >> 5;
    float a = 0.f;
#pragma unroll
    for (int k = 0; k < 16; ++k) {
        int kk = half * 16 + k;
        a += h[wv][kk] * Wb[kk * DIM + col];
    }
    a += __shfl_xor(a, 32, 64);
    a += shb[col];
    float hp = a > 0.f ? a : expm1f(a);
    if (half == 0) {
        xnext[(size_t)node * DIM + col] = hp;
        // pack bf16 pairs: even-col lanes store one uint covering cols (col, col+1)
        float hn = __shfl_down(hp, 1, 64);
        if ((col & 1) == 0) {
            unsigned pk = (unsigned)f2bf(hp) | ((unsigned)f2bf(hn) << 16);
            *(unsigned*)(xnextb + (size_t)node * DIM + col) = pk;
        }
    }
}

// ===== lin MLP + Z accumulate + segment-max, barrier-free shuffle version =====
// Wave owns 16 contiguous rows; 2 rows/iter via 64 contiguous loads + shfl broadcast.
#define LIN_ROWS_PER_BLOCK 64
template <bool FIRST>
__global__ __launch_bounds__(256) void linZ_kernel(
        const float* __restrict__ h,       // [N,32]
        const float* __restrict__ Wf, const float* __restrict__ shf,
        const int* __restrict__ batch,     // [N] sorted
        const float* __restrict__ lw_ptr,
        float* __restrict__ Z,             // [N,32]
        unsigned* __restrict__ segmax)     // [G,32] encoded
{
    __shared__ float Wl[DIM * DIM];
    __shared__ float sh[DIM];
    __shared__ unsigned segloc[8 * DIM];
    int t = threadIdx.x;
    for (int i = t; i < DIM * DIM; i += 256) Wl[i] = Wf[i];
    if (t < DIM) sh[t] = shf[t];
    if (t < 8 * DIM) segloc[t] = 0;
    __syncthreads();

    int wv = t >> 6, lane = t & 63;
    int half = lane >> 5, col = lane & 31;
    int blk0 = blockIdx.x * LIN_ROWS_PER_BLOCK;
    int r0 = blk0 + wv * 16;
    int gfirst = batch[blk0];
    float lw = lw_ptr[0];

    float m = 0.f;
    int gcur = -1;

    for (int i = 0; i < 16; i += 2) {
        int r = r0 + i;                        // rows r (half 0), r+1 (half 1); N even
        if (r >= N_NODES) break;
        float v = h[(size_t)r * DIM + lane];   // 256 B contiguous per wave
        float a = sh[col];
#pragma unroll
        for (int k = 0; k < DIM; ++k)
            a += __shfl(v, half * 32 + k, 64) * Wl[k * DIM + col];
        float z = a > 0.f ? a : expm1f(a);
        float zw = lw * z;
        size_t zi = (size_t)r * DIM + lane;    // == (r+half)*32 + col
        if (FIRST) Z[zi] = zw;
        else       Z[zi] += zw;

        float segval = FIRST ? z : zw;         // layer 0 pools unweighted z
        int g = batch[r + half];
        if (g != gcur) {
            if (gcur >= 0) {
                int go = gcur - gfirst;
                unsigned en = enc_f32(m);
                if (go < 8) atomicMax(&segloc[go * DIM + col], en);
                else        atomicMax(&segmax[gcur * DIM + col], en);
            }
            gcur = g;
            m = segval;
        } else {
            m = fmaxf(m, segval);
        }
    }
    if (gcur >= 0) {
        int go = gcur - gfirst;
        unsigned en = enc_f32(m);
        if (go < 8) atomicMax(&segloc[go * DIM + col], en);
        else        atomicMax(&segmax[gcur * DIM + col], en);
    }
    __syncthreads();
    if (t < 8 * DIM) {
        unsigned v = segloc[t];
        if (v) atomicMax(&segmax[(gfirst + (t >> 5)) * DIM + (t & 31)], v);
    }
}

// out[g][j] += decode(segmax[g][j])
__global__ void add_out_kernel(const unsigned* __restrict__ segmax, float* __restrict__ out) {
    int t = blockIdx.x * blockDim.x + threadIdx.x;  // 2048
    out[t] += dec_f32(segmax[t]);
}

extern "C" void kernel_launch(void* const* d_in, const int* in_sizes, int n_in,
                              void* d_out, int out_size, void* d_ws, size_t ws_size,
                              hipStream_t stream) {
    const float* x0        = (const float*)d_in[0];
    const int*   ei        = (const int*)d_in[1];     // (2,E): row0=src, row1=dst
    const int*   batch     = (const int*)d_in[2];
    const float* lw        = (const float*)d_in[3];
    const float* lin_W     = (const float*)d_in[4];
    const float* lin_b     = (const float*)d_in[5];
    const float* lin_gamma = (const float*)d_in[6];
    const float* lin_beta  = (const float*)d_in[7];
    const float* lin_mean  = (const float*)d_in[8];
    const float* lin_var   = (const float*)d_in[9];
    const float* conv_W    = (const float*)d_in[10];
    const float* conv_b    = (const float*)d_in[11];
    const float* conv_gamma= (const float*)d_in[12];
    const float* conv_beta = (const float*)d_in[13];
    const float* conv_mean = (const float*)d_in[14];
    const float* conv_var  = (const float*)d_in[15];

    float* out  = (float*)d_out;                 // [G*32]
    float* Z    = out + N_GROUPS * DIM;          // [N*32]
    float* xout = Z + (size_t)N_NODES * DIM;     // [N*32] final x

    char* p = (char*)d_ws;
    float*          xbuf   = (float*)p;          p += (size_t)N_NODES * DIM * sizeof(float);
    unsigned short* x0b    = (unsigned short*)p; p += (size_t)N_NODES * DIM * sizeof(unsigned short);
    unsigned short* xbufb  = (unsigned short*)p; p += (size_t)N_NODES * DIM * sizeof(unsigned short);
    unsigned*       binbuf = (unsigned*)p;       p += (size_t)N_EDGES * sizeof(unsigned);
    int*            esrc   = (int*)p;            p += (size_t)N_EDGES * sizeof(int);
    int*            nodeptr= (int*)p;            p += (NBINS * BIN_NODES + 1) * sizeof(int);
    int*            bincnt = (int*)p;            p += NBINS * sizeof(int);
    int*            binoff = (int*)p;            p += (NBINS + 1) * sizeof(int);
    int*            bincur = (int*)p;            p += NBINS * sizeof(int);
    unsigned*       segmx  = (unsigned*)p;       p += N_GROUPS * DIM * sizeof(unsigned);
    float*          Wf     = (float*)p;          p += 5 * DIM * DIM * sizeof(float);
    float*          shf    = (float*)p;          p += 5 * DIM * sizeof(float);

    const int* src = ei;
    const int* dst = ei + N_EDGES;

    const int linZ_blocks = (N_NODES + LIN_ROWS_PER_BLOCK - 1) / LIN_ROWS_PER_BLOCK;  // 1563
    const int gc_blocks   = N_NODES / 4;            // 25000
    const int cvt_blocks  = N_NODES * DIM / 4 / 256; // 3125

    hipMemsetAsync(out, 0, N_GROUPS * DIM * sizeof(float), stream);
    hipMemsetAsync(bincnt, 0, NBINS * sizeof(int), stream);
    fold_kernel<<<5, 1024, 0, stream>>>(lin_W, lin_b, lin_gamma, lin_beta, lin_mean, lin_var,
                                        conv_W, conv_b, conv_gamma, conv_beta, conv_mean, conv_var,
                                        Wf, shf);

    // ---- CSR build + bf16 copy of x0 ----
    binhist_kernel<<<HIST_BLOCKS, 256, 0, stream>>>(dst, bincnt);
    binscan_kernel<<<1, 1024, 0, stream>>>(bincnt, binoff, bincur);
    binscatter_kernel<<<HIST_BLOCKS, 256, 0, stream>>>(src, dst, bincur, binbuf);
    binsort_kernel<<<NBINS, 256, 0, stream>>>(binbuf, binoff, esrc, nodeptr);
    convert_kernel<<<cvt_blocks, 256, 0, stream>>>(x0, x0b);

    // ---- layer 0 ----
    hipMemsetAsync(segmx, 0, N_GROUPS * DIM * sizeof(unsigned), stream);
    linZ_kernel<true><<<linZ_blocks, 256, 0, stream>>>(x0, Wf, shf, batch, lw, Z, segmx);
    add_out_kernel<<<8, 256, 0, stream>>>(segmx, out);

    // ---- layer 1 ----
    gatherconv_kernel<<<gc_blocks, 256, 0, stream>>>(x0, x0b, esrc, nodeptr,
                                                     Wf + 3 * DIM * DIM, shf + 3 * DIM,
                                                     xbuf, xbufb);
    hipMemsetAsync(segmx, 0, N_GROUPS * DIM * sizeof(unsigned), stream);
    linZ_kernel<false><<<linZ_blocks, 256, 0, stream>>>(xbuf, Wf + 1 * DIM * DIM, shf + 1 * DIM,
                                                        batch, lw + 1, Z, segmx);
    add_out_kernel<<<8, 256, 0, stream>>>(segmx, out);

    // ---- layer 2 ----
    gatherconv_kernel<<<gc_blocks, 256, 0, stream>>>(xbuf, xbufb, esrc, nodeptr,
                                                     Wf + 4 * DIM * DIM, shf + 4 * DIM,
                                                     xout, x0b /*dead but uniform work*/);
    hipMemsetAsync(segmx, 0, N_GROUPS * DIM * sizeof(unsigned), stream);
    linZ_kernel<false><<<linZ_blocks, 256, 0, stream>>>(xout, Wf + 2 * DIM * DIM, shf + 2 * DIM,
                                                        batch, lw + 2, Z, segmx);
    add_out_kernel<<<8, 256, 0, stream>>>(segmx, out);
}

// Round 8
// 381.443 us; speedup vs baseline: 1.0462x; 1.0462x over previous
//
#include <hip/hip_runtime.h>
#include <math.h>

#define N_NODES 100000
#define N_EDGES 1600000
#define DIM 32
#define N_GROUPS 64
#define BN_EPS 1e-5f

#define BIN_NODES 128
#define NBINS ((N_NODES + BIN_NODES - 1) / BIN_NODES)   // 782
#define EPB_HIST 8192
#define HIST_BLOCKS ((N_EDGES + EPB_HIST - 1) / EPB_HIST)  // 196

// ---- monotone float<->uint encoding for atomic max on floats ----
__device__ __forceinline__ unsigned enc_f32(float f) {
    unsigned u = __float_as_uint(f);
    return (u & 0x80000000u) ? ~u : (u | 0x80000000u);
}
__device__ __forceinline__ float dec_f32(unsigned u) {
    return (u & 0x80000000u) ? __uint_as_float(u & 0x7FFFFFFFu) : __uint_as_float(~u);
}
// fp32 -> bf16 bits (RNE)
__device__ __forceinline__ unsigned short f2bf(float f) {
    unsigned u = __float_as_uint(f);
    u += 0x7FFFu + ((u >> 16) & 1u);
    return (unsigned short)(u >> 16);
}

// Fold BN into weights
__global__ void fold_kernel(const float* __restrict__ lin_W, const float* __restrict__ lin_b,
                            const float* __restrict__ lin_gamma, const float* __restrict__ lin_beta,
                            const float* __restrict__ lin_mean, const float* __restrict__ lin_var,
                            const float* __restrict__ conv_W, const float* __restrict__ conv_b,
                            const float* __restrict__ conv_gamma, const float* __restrict__ conv_beta,
                            const float* __restrict__ conv_mean, const float* __restrict__ conv_var,
                            float* __restrict__ Wf, float* __restrict__ shf)
{
    int l = blockIdx.x;      // 0..2 = lin, 3..4 = conv
    int t = threadIdx.x;
    const float *W, *b, *gm, *bt, *mn, *vr;
    if (l < 3) {
        W = lin_W + l * DIM * DIM; b = lin_b + l * DIM; gm = lin_gamma + l * DIM;
        bt = lin_beta + l * DIM;   mn = lin_mean + l * DIM; vr = lin_var + l * DIM;
    } else {
        int c = l - 3;
        W = conv_W + c * DIM * DIM; b = conv_b + c * DIM; gm = conv_gamma + c * DIM;
        bt = conv_beta + c * DIM;   mn = conv_mean + c * DIM; vr = conv_var + c * DIM;
    }
    int j = t & (DIM - 1);
    float scale = gm[j] / sqrtf(vr[j] + BN_EPS);
    Wf[l * DIM * DIM + t] = W[t] * scale;
    if (t < DIM) shf[l * DIM + t] = (b[t] - mn[t]) * scale + bt[t];
}

// x (fp32) -> xb (bf16 bits), 4 elems/thread
__global__ __launch_bounds__(256) void convert_kernel(const float* __restrict__ x,
                                                      unsigned short* __restrict__ xb) {
    int i = blockIdx.x * 256 + threadIdx.x;          // grid exact: N*DIM/4/256
    float4 v = ((const float4*)x)[i];
    uint2 o;
    o.x = (unsigned)f2bf(v.x) | ((unsigned)f2bf(v.y) << 16);
    o.y = (unsigned)f2bf(v.z) | ((unsigned)f2bf(v.w) << 16);
    ((uint2*)xb)[i] = o;
}

// ================= bin-grouped edge build =================
// binhist also persists per-(block,bin) counts so binscatter can skip its count pass.
__global__ __launch_bounds__(256) void binhist_kernel(const int* __restrict__ dst,
                                                      int* __restrict__ bincnt,
                                                      int* __restrict__ blockcnt) {
    __shared__ int cnt[NBINS];
    int t = threadIdx.x;
    for (int b = t; b < NBINS; b += 256) cnt[b] = 0;
    __syncthreads();
    int base = blockIdx.x * EPB_HIST;
    for (int i = 0; i < EPB_HIST / 256; ++i) {
        int e = base + i * 256 + t;
        if (e < N_EDGES) atomicAdd(&cnt[dst[e] >> 7], 1);
    }
    __syncthreads();
    for (int b = t; b < NBINS; b += 256) {
        int c = cnt[b];
        blockcnt[(size_t)blockIdx.x * NBINS + b] = c;
        if (c > 0) atomicAdd(&bincnt[b], c);
    }
}

__global__ __launch_bounds__(1024) void binscan_kernel(const int* __restrict__ bincnt,
                                                       int* __restrict__ binoff,
                                                       int* __restrict__ bincur) {
    __shared__ int s[1024];
    int t = threadIdx.x;
    int c = (t < NBINS) ? bincnt[t] : 0;
    s[t] = c;
    __syncthreads();
    for (int off = 1; off < 1024; off <<= 1) {
        int u = (t >= off) ? s[t - off] : 0;
        __syncthreads();
        s[t] += u;
        __syncthreads();
    }
    if (t < NBINS) { binoff[t] = s[t] - c; bincur[t] = s[t] - c; }
    if (t == 0) binoff[NBINS] = N_EDGES;
}

// Uses blockcnt from binhist: reserve per-(block,bin) range, then place.
__global__ __launch_bounds__(256) void binscatter_kernel(const int* __restrict__ src,
                                                         const int* __restrict__ dst,
                                                         int* __restrict__ bincur,
                                                         unsigned* __restrict__ binbuf,
                                                         const int* __restrict__ blockcnt) {
    __shared__ int pos[NBINS];
    int t = threadIdx.x;
    for (int b = t; b < NBINS; b += 256) {
        int c = blockcnt[(size_t)blockIdx.x * NBINS + b];
        pos[b] = (c > 0) ? atomicAdd(&bincur[b], c) : 0;
    }
    __syncthreads();
    int base = blockIdx.x * EPB_HIST;
    for (int i = 0; i < EPB_HIST / 256; ++i) {
        int e = base + i * 256 + t;
        if (e < N_EDGES) {
            int d = dst[e];
            int bin = d >> 7;
            int p = atomicAdd(&pos[bin], 1);
            binbuf[p] = ((unsigned)(d & 127) << 17) | (unsigned)src[e];
        }
    }
}

// counting sort within bin -> exact per-node CSR
__global__ __launch_bounds__(256) void binsort_kernel(const unsigned* __restrict__ binbuf,
                                                      const int* __restrict__ binoff,
                                                      int* __restrict__ esrc,
                                                      int* __restrict__ nodeptr) {
    __shared__ int cnt[BIN_NODES];
    __shared__ int sc[BIN_NODES];
    int t = threadIdx.x;
    int bin = blockIdx.x;
    int beg = binoff[bin], end = binoff[bin + 1];
    if (t < BIN_NODES) cnt[t] = 0;
    __syncthreads();
    for (int e = beg + t; e < end; e += 256)
        atomicAdd(&cnt[binbuf[e] >> 17], 1);
    __syncthreads();
    int v = (t < BIN_NODES) ? cnt[t] : 0;
    if (t < BIN_NODES) sc[t] = v;
    __syncthreads();
    for (int off = 1; off < BIN_NODES; off <<= 1) {
        int u = (t < BIN_NODES && t >= off) ? sc[t - off] : 0;
        __syncthreads();
        if (t < BIN_NODES) sc[t] += u;
        __syncthreads();
    }
    if (t < BIN_NODES) {
        int excl = sc[t] - v;
        cnt[t] = excl;
        nodeptr[bin * BIN_NODES + t] = beg + excl;
    }
    __syncthreads();
    for (int e = beg + t; e < end; e += 256) {
        unsigned pe = binbuf[e];
        int dl = (int)(pe >> 17);
        int p = atomicAdd(&cnt[dl], 1);
        esrc[beg + p] = (int)(pe & 0x1FFFFu);
    }
}

// ===== fused gather(bf16) + conv-MLP, v2 =====
// 16 edge-slots x 4 col-chunks (uint4/lane), 4 serial nodes per wave, 16 nodes/block
// (W staged once per 16 nodes). xnextb==nullptr skips the bf16 mirror store.
#define GC_NODES_PER_BLOCK 16
__global__ __launch_bounds__(256) void gatherconv_kernel(
        const float* __restrict__ x,              // fp32 layer input
        const unsigned short* __restrict__ xb,    // bf16 bits of same
        const int* __restrict__ esrc,
        const int* __restrict__ nodeptr,
        const float* __restrict__ Wc, const float* __restrict__ shc,
        float* __restrict__ xnext,
        unsigned short* __restrict__ xnextb)      // may be nullptr
{
    __shared__ float Wb[DIM * DIM];
    __shared__ float shb[DIM];
    __shared__ float h[4][DIM];
    int t = threadIdx.x;
    for (int i = t; i < DIM * DIM; i += 256) Wb[i] = Wc[i];
    if (t < DIM) shb[t] = shc[t];
    __syncthreads();

    int wv = t >> 6, lane = t & 63;
    int slot = lane >> 2;            // 0..15 edge slots
    int chunk = lane & 3;            // cols chunk*8 .. +8
    int col = lane & 31, half = lane >> 5;
    int nbase = blockIdx.x * GC_NODES_PER_BLOCK + wv * 4;

    for (int ni = 0; ni < 4; ++ni) {
        int node = nbase + ni;
        int beg = nodeptr[node], end = nodeptr[node + 1];
        float acc[8] = {0.f, 0.f, 0.f, 0.f, 0.f, 0.f, 0.f, 0.f};
        for (int e = beg + slot; e < end; e += 16) {
            int s = esrc[e];
            uint4 u = *(const uint4*)(xb + (size_t)s * DIM + chunk * 8);  // 8 bf16 = 16 B
            acc[0] += __uint_as_float(u.x << 16);
            acc[1] += __uint_as_float(u.x & 0xFFFF0000u);
            acc[2] += __uint_as_float(u.y << 16);
            acc[3] += __uint_as_float(u.y & 0xFFFF0000u);
            acc[4] += __uint_as_float(u.z << 16);
            acc[5] += __uint_as_float(u.z & 0xFFFF0000u);
            acc[6] += __uint_as_float(u.w << 16);
            acc[7] += __uint_as_float(u.w & 0xFFFF0000u);
        }
#pragma unroll
        for (int off = 4; off < 64; off <<= 1) {
#pragma unroll
            for (int i2 = 0; i2 < 8; ++i2)
                acc[i2] += __shfl_xor(acc[i2], off, 64);
        }
        if (slot == 0) {             // lanes 0-3: add self row, publish h (same-wave LDS)
            const float4 s0 = *(const float4*)(x + (size_t)node * DIM + chunk * 8);
            const float4 s1 = *(const float4*)(x + (size_t)node * DIM + chunk * 8 + 4);
            float4 r0 = make_float4(acc[0] + s0.x, acc[1] + s0.y, acc[2] + s0.z, acc[3] + s0.w);
            float4 r1 = make_float4(acc[4] + s1.x, acc[5] + s1.y, acc[6] + s1.z, acc[7] + s1.w);
            *(float4*)(&h[wv][chunk * 8]) = r0;
            *(float4*)(&h[wv][chunk * 8 + 4]) = r1;
        }
        float a = 0.f;
#pragma unroll
        for (int k = 0; k < 16; ++k) {
            int kk = half * 16 + k;
            a += h[wv][kk] * Wb[kk * DIM + col];
        }
        a += __shfl_xor(a, 32, 64);
        a += shb[col];
        float hp = a > 0.f ? a : expm1f(a);
        if (half == 0) {
            xnext[(size_t)node * DIM + col] = hp;
            if (xnextb) {
                float hn = __shfl_down(hp, 1, 64);
                if ((col & 1) == 0) {
                    unsigned pk = (unsigned)f2bf(hp) | ((unsigned)f2bf(hn) << 16);
                    *(unsigned*)(xnextb + (size_t)node * DIM + col) = pk;
                }
            }
        }
    }
}

// ===== lin MLP + Z accumulate + segment-max, barrier-free shuffle version =====
#define LIN_ROWS_PER_BLOCK 64
template <bool FIRST>
__global__ __launch_bounds__(256) void linZ_kernel(
        const float* __restrict__ h,       // [N,32]
        const float* __restrict__ Wf, const float* __restrict__ shf,
        const int* __restrict__ batch,     // [N] sorted
        const float* __restrict__ lw_ptr,
        float* __restrict__ Z,             // [N,32]
        unsigned* __restrict__ segmax)     // [G,32] encoded
{
    __shared__ float Wl[DIM * DIM];
    __shared__ float sh[DIM];
    __shared__ unsigned segloc[8 * DIM];
    int t = threadIdx.x;
    for (int i = t; i < DIM * DIM; i += 256) Wl[i] = Wf[i];
    if (t < DIM) sh[t] = shf[t];
    if (t < 8 * DIM) segloc[t] = 0;
    __syncthreads();

    int wv = t >> 6, lane = t & 63;
    int half = lane >> 5, col = lane & 31;
    int blk0 = blockIdx.x * LIN_ROWS_PER_BLOCK;
    int r0 = blk0 + wv * 16;
    int gfirst = batch[blk0];
    float lw = lw_ptr[0];

    float m = 0.f;
    int gcur = -1;

    for (int i = 0; i < 16; i += 2) {
        int r = r0 + i;
        if (r >= N_NODES) break;
        float v = h[(size_t)r * DIM + lane];
        float a = sh[col];
#pragma unroll
        for (int k = 0; k < DIM; ++k)
            a += __shfl(v, half * 32 + k, 64) * Wl[k * DIM + col];
        float z = a > 0.f ? a : expm1f(a);
        float zw = lw * z;
        size_t zi = (size_t)r * DIM + lane;
        if (FIRST) Z[zi] = zw;
        else       Z[zi] += zw;

        float segval = FIRST ? z : zw;
        int g = batch[r + half];
        if (g != gcur) {
            if (gcur >= 0) {
                int go = gcur - gfirst;
                unsigned en = enc_f32(m);
                if (go < 8) atomicMax(&segloc[go * DIM + col], en);
                else        atomicMax(&segmax[gcur * DIM + col], en);
            }
            gcur = g;
            m = segval;
        } else {
            m = fmaxf(m, segval);
        }
    }
    if (gcur >= 0) {
        int go = gcur - gfirst;
        unsigned en = enc_f32(m);
        if (go < 8) atomicMax(&segloc[go * DIM + col], en);
        else        atomicMax(&segmax[gcur * DIM + col], en);
    }
    __syncthreads();
    if (t < 8 * DIM) {
        unsigned v = segloc[t];
        if (v) atomicMax(&segmax[(gfirst + (t >> 5)) * DIM + (t & 31)], v);
    }
}

// out[g][j] += decode(segmax[g][j]); reset segmax for the next layer's atomics.
__global__ void add_out_kernel(unsigned* __restrict__ segmax, float* __restrict__ out) {
    int t = blockIdx.x * blockDim.x + threadIdx.x;  // 2048
    out[t] += dec_f32(segmax[t]);
    segmax[t] = 0;
}

extern "C" void kernel_launch(void* const* d_in, const int* in_sizes, int n_in,
                              void* d_out, int out_size, void* d_ws, size_t ws_size,
                              hipStream_t stream) {
    const float* x0        = (const float*)d_in[0];
    const int*   ei        = (const int*)d_in[1];     // (2,E): row0=src, row1=dst
    const int*   batch     = (const int*)d_in[2];
    const float* lw        = (const float*)d_in[3];
    const float* lin_W     = (const float*)d_in[4];
    const float* lin_b     = (const float*)d_in[5];
    const float* lin_gamma = (const float*)d_in[6];
    const float* lin_beta  = (const float*)d_in[7];
    const float* lin_mean  = (const float*)d_in[8];
    const float* lin_var   = (const float*)d_in[9];
    const float* conv_W    = (const float*)d_in[10];
    const float* conv_b    = (const float*)d_in[11];
    const float* conv_gamma= (const float*)d_in[12];
    const float* conv_beta = (const float*)d_in[13];
    const float* conv_mean = (const float*)d_in[14];
    const float* conv_var  = (const float*)d_in[15];

    float* out  = (float*)d_out;                 // [G*32]
    float* Z    = out + N_GROUPS * DIM;          // [N*32]
    float* xout = Z + (size_t)N_NODES * DIM;     // [N*32] final x

    char* p = (char*)d_ws;
    float*          xbuf    = (float*)p;          p += (size_t)N_NODES * DIM * sizeof(float);
    unsigned short* x0b     = (unsigned short*)p; p += (size_t)N_NODES * DIM * sizeof(unsigned short);
    unsigned short* xbufb   = (unsigned short*)p; p += (size_t)N_NODES * DIM * sizeof(unsigned short);
    unsigned*       binbuf  = (unsigned*)p;       p += (size_t)N_EDGES * sizeof(unsigned);
    int*            esrc    = (int*)p;            p += (size_t)N_EDGES * sizeof(int);
    int*            nodeptr = (int*)p;            p += (NBINS * BIN_NODES + 1) * sizeof(int);
    int*            blockcnt= (int*)p;            p += (size_t)HIST_BLOCKS * NBINS * sizeof(int);
    int*            bincnt  = (int*)p;            p += NBINS * sizeof(int);
    int*            binoff  = (int*)p;            p += (NBINS + 1) * sizeof(int);
    int*            bincur  = (int*)p;            p += NBINS * sizeof(int);
    unsigned*       segmx   = (unsigned*)p;       p += N_GROUPS * DIM * sizeof(unsigned);
    float*          Wf      = (float*)p;          p += 5 * DIM * DIM * sizeof(float);
    float*          shf     = (float*)p;          p += 5 * DIM * sizeof(float);

    const int* src = ei;
    const int* dst = ei + N_EDGES;

    const int linZ_blocks = (N_NODES + LIN_ROWS_PER_BLOCK - 1) / LIN_ROWS_PER_BLOCK;  // 1563
    const int gc_blocks   = (N_NODES + GC_NODES_PER_BLOCK - 1) / GC_NODES_PER_BLOCK;  // 6250
    const int cvt_blocks  = N_NODES * DIM / 4 / 256;                                  // 3125

    hipMemsetAsync(out, 0, N_GROUPS * DIM * sizeof(float), stream);
    hipMemsetAsync(bincnt, 0, NBINS * sizeof(int), stream);
    hipMemsetAsync(segmx, 0, N_GROUPS * DIM * sizeof(unsigned), stream);
    fold_kernel<<<5, 1024, 0, stream>>>(lin_W, lin_b, lin_gamma, lin_beta, lin_mean, lin_var,
                                        conv_W, conv_b, conv_gamma, conv_beta, conv_mean, conv_var,
                                        Wf, shf);

    // ---- CSR build + bf16 copy of x0 ----
    binhist_kernel<<<HIST_BLOCKS, 256, 0, stream>>>(dst, bincnt, blockcnt);
    binscan_kernel<<<1, 1024, 0, stream>>>(bincnt, binoff, bincur);
    binscatter_kernel<<<HIST_BLOCKS, 256, 0, stream>>>(src, dst, bincur, binbuf, blockcnt);
    binsort_kernel<<<NBINS, 256, 0, stream>>>(binbuf, binoff, esrc, nodeptr);
    convert_kernel<<<cvt_blocks, 256, 0, stream>>>(x0, x0b);

    // ---- layer 0 ----
    linZ_kernel<true><<<linZ_blocks, 256, 0, stream>>>(x0, Wf, shf, batch, lw, Z, segmx);
    add_out_kernel<<<8, 256, 0, stream>>>(segmx, out);

    // ---- layer 1 ----
    gatherconv_kernel<<<gc_blocks, 256, 0, stream>>>(x0, x0b, esrc, nodeptr,
                                                     Wf + 3 * DIM * DIM, shf + 3 * DIM,
                                                     xbuf, xbufb);
    linZ_kernel<false><<<linZ_blocks, 256, 0, stream>>>(xbuf, Wf + 1 * DIM * DIM, shf + 1 * DIM,
                                                        batch, lw + 1, Z, segmx);
    add_out_kernel<<<8, 256, 0, stream>>>(segmx, out);

    // ---- layer 2 ----
    gatherconv_kernel<<<gc_blocks, 256, 0, stream>>>(xbuf, xbufb, esrc, nodeptr,
                                                     Wf + 4 * DIM * DIM, shf + 4 * DIM,
                                                     xout, (unsigned short*)nullptr);
    linZ_kernel<false><<<linZ_blocks, 256, 0, stream>>>(xout, Wf + 2 * DIM * DIM, shf + 2 * DIM,
                                                        batch, lw + 2, Z, segmx);
    add_out_kernel<<<8, 256, 0, stream>>>(segmx, out);
}

// Round 9
// 324.246 us; speedup vs baseline: 1.2308x; 1.1764x over previous
//
#include <hip/hip_runtime.h>
#include <math.h>
#include <string.h>

#define N_NODES 100000
#define N_EDGES 1600000
#define DIM 32
#define N_GROUPS 64
#define BN_EPS 1e-5f

#define BIN_NODES 128
#define NBINS ((N_NODES + BIN_NODES - 1) / BIN_NODES)   // 782
#define EPB_HIST 8192
#define HIST_BLOCKS ((N_EDGES + EPB_HIST - 1) / EPB_HIST)  // 196

typedef __attribute__((ext_vector_type(8))) short short8;   // 8 bf16 (4 VGPRs)
typedef __attribute__((ext_vector_type(4))) float f32x4;

// ---- monotone float<->uint encoding for atomic max on floats ----
__device__ __forceinline__ unsigned enc_f32(float f) {
    unsigned u = __float_as_uint(f);
    return (u & 0x80000000u) ? ~u : (u | 0x80000000u);
}
__device__ __forceinline__ float dec_f32(unsigned u) {
    return (u & 0x80000000u) ? __uint_as_float(u & 0x7FFFFFFFu) : __uint_as_float(~u);
}
// fp32 -> bf16 bits (RNE)
__device__ __forceinline__ unsigned short f2bf(float f) {
    unsigned u = __float_as_uint(f);
    u += 0x7FFFu + ((u >> 16) & 1u);
    return (unsigned short)(u >> 16);
}

// Fold BN into weights; also emit bf16 copy of folded W for the MFMA lin path.
__global__ void fold_kernel(const float* __restrict__ lin_W, const float* __restrict__ lin_b,
                            const float* __restrict__ lin_gamma, const float* __restrict__ lin_beta,
                            const float* __restrict__ lin_mean, const float* __restrict__ lin_var,
                            const float* __restrict__ conv_W, const float* __restrict__ conv_b,
                            const float* __restrict__ conv_gamma, const float* __restrict__ conv_beta,
                            const float* __restrict__ conv_mean, const float* __restrict__ conv_var,
                            float* __restrict__ Wf, float* __restrict__ shf,
                            unsigned short* __restrict__ Wfb)
{
    int l = blockIdx.x;      // 0..2 = lin, 3..4 = conv
    int t = threadIdx.x;
    const float *W, *b, *gm, *bt, *mn, *vr;
    if (l < 3) {
        W = lin_W + l * DIM * DIM; b = lin_b + l * DIM; gm = lin_gamma + l * DIM;
        bt = lin_beta + l * DIM;   mn = lin_mean + l * DIM; vr = lin_var + l * DIM;
    } else {
        int c = l - 3;
        W = conv_W + c * DIM * DIM; b = conv_b + c * DIM; gm = conv_gamma + c * DIM;
        bt = conv_beta + c * DIM;   mn = conv_mean + c * DIM; vr = conv_var + c * DIM;
    }
    int j = t & (DIM - 1);
    float scale = gm[j] / sqrtf(vr[j] + BN_EPS);
    float w = W[t] * scale;
    Wf[l * DIM * DIM + t] = w;
    Wfb[l * DIM * DIM + t] = f2bf(w);
    if (t < DIM) shf[l * DIM + t] = (b[t] - mn[t]) * scale + bt[t];
}

// x (fp32) -> xb (bf16 bits), 4 elems/thread
__global__ __launch_bounds__(256) void convert_kernel(const float* __restrict__ x,
                                                      unsigned short* __restrict__ xb) {
    int i = blockIdx.x * 256 + threadIdx.x;          // grid exact: N*DIM/4/256
    float4 v = ((const float4*)x)[i];
    uint2 o;
    o.x = (unsigned)f2bf(v.x) | ((unsigned)f2bf(v.y) << 16);
    o.y = (unsigned)f2bf(v.z) | ((unsigned)f2bf(v.w) << 16);
    ((uint2*)xb)[i] = o;
}

// ================= bin-grouped edge build =================
__global__ __launch_bounds__(256) void binhist_kernel(const int* __restrict__ dst,
                                                      int* __restrict__ bincnt,
                                                      int* __restrict__ blockcnt) {
    __shared__ int cnt[NBINS];
    int t = threadIdx.x;
    for (int b = t; b < NBINS; b += 256) cnt[b] = 0;
    __syncthreads();
    int base = blockIdx.x * EPB_HIST;
    for (int i = 0; i < EPB_HIST / 256; ++i) {
        int e = base + i * 256 + t;
        if (e < N_EDGES) atomicAdd(&cnt[dst[e] >> 7], 1);
    }
    __syncthreads();
    for (int b = t; b < NBINS; b += 256) {
        int c = cnt[b];
        blockcnt[(size_t)blockIdx.x * NBINS + b] = c;
        if (c > 0) atomicAdd(&bincnt[b], c);
    }
}

__global__ __launch_bounds__(1024) void binscan_kernel(const int* __restrict__ bincnt,
                                                       int* __restrict__ binoff,
                                                       int* __restrict__ bincur) {
    __shared__ int s[1024];
    int t = threadIdx.x;
    int c = (t < NBINS) ? bincnt[t] : 0;
    s[t] = c;
    __syncthreads();
    for (int off = 1; off < 1024; off <<= 1) {
        int u = (t >= off) ? s[t - off] : 0;
        __syncthreads();
        s[t] += u;
        __syncthreads();
    }
    if (t < NBINS) { binoff[t] = s[t] - c; bincur[t] = s[t] - c; }
    if (t == 0) binoff[NBINS] = N_EDGES;
}

__global__ __launch_bounds__(256) void binscatter_kernel(const int* __restrict__ src,
                                                         const int* __restrict__ dst,
                                                         int* __restrict__ bincur,
                                                         unsigned* __restrict__ binbuf,
                                                         const int* __restrict__ blockcnt) {
    __shared__ int pos[NBINS];
    int t = threadIdx.x;
    for (int b = t; b < NBINS; b += 256) {
        int c = blockcnt[(size_t)blockIdx.x * NBINS + b];
        pos[b] = (c > 0) ? atomicAdd(&bincur[b], c) : 0;
    }
    __syncthreads();
    int base = blockIdx.x * EPB_HIST;
    for (int i = 0; i < EPB_HIST / 256; ++i) {
        int e = base + i * 256 + t;
        if (e < N_EDGES) {
            int d = dst[e];
            int bin = d >> 7;
            int p = atomicAdd(&pos[bin], 1);
            binbuf[p] = ((unsigned)(d & 127) << 17) | (unsigned)src[e];
        }
    }
}

// counting sort within bin -> exact per-node CSR
__global__ __launch_bounds__(256) void binsort_kernel(const unsigned* __restrict__ binbuf,
                                                      const int* __restrict__ binoff,
                                                      int* __restrict__ esrc,
                                                      int* __restrict__ nodeptr) {
    __shared__ int cnt[BIN_NODES];
    __shared__ int sc[BIN_NODES];
    int t = threadIdx.x;
    int bin = blockIdx.x;
    int beg = binoff[bin], end = binoff[bin + 1];
    if (t < BIN_NODES) cnt[t] = 0;
    __syncthreads();
    for (int e = beg + t; e < end; e += 256)
        atomicAdd(&cnt[binbuf[e] >> 17], 1);
    __syncthreads();
    int v = (t < BIN_NODES) ? cnt[t] : 0;
    if (t < BIN_NODES) sc[t] = v;
    __syncthreads();
    for (int off = 1; off < BIN_NODES; off <<= 1) {
        int u = (t < BIN_NODES && t >= off) ? sc[t - off] : 0;
        __syncthreads();
        if (t < BIN_NODES) sc[t] += u;
        __syncthreads();
    }
    if (t < BIN_NODES) {
        int excl = sc[t] - v;
        cnt[t] = excl;
        nodeptr[bin * BIN_NODES + t] = beg + excl;
    }
    __syncthreads();
    for (int e = beg + t; e < end; e += 256) {
        unsigned pe = binbuf[e];
        int dl = (int)(pe >> 17);
        int p = atomicAdd(&cnt[dl], 1);
        esrc[beg + p] = (int)(pe & 0x1FFFFu);
    }
}

// ===== fused gather(bf16) + conv-MLP (R8 structure) =====
#define GC_NODES_PER_BLOCK 16
__global__ __launch_bounds__(256) void gatherconv_kernel(
        const float* __restrict__ x,              // fp32 layer input
        const unsigned short* __restrict__ xb,    // bf16 bits of same
        const int* __restrict__ esrc,
        const int* __restrict__ nodeptr,
        const float* __restrict__ Wc, const float* __restrict__ shc,
        float* __restrict__ xnext,
        unsigned short* __restrict__ xnextb)
{
    __shared__ float Wb[DIM * DIM];
    __shared__ float shb[DIM];
    __shared__ float h[4][DIM];
    int t = threadIdx.x;
    for (int i = t; i < DIM * DIM; i += 256) Wb[i] = Wc[i];
    if (t < DIM) shb[t] = shc[t];
    __syncthreads();

    int wv = t >> 6, lane = t & 63;
    int slot = lane >> 2;            // 0..15 edge slots
    int chunk = lane & 3;            // cols chunk*8 .. +8
    int col = lane & 31, half = lane >> 5;
    int nbase = blockIdx.x * GC_NODES_PER_BLOCK + wv * 4;

    for (int ni = 0; ni < 4; ++ni) {
        int node = nbase + ni;
        int beg = nodeptr[node], end = nodeptr[node + 1];
        float acc[8] = {0.f, 0.f, 0.f, 0.f, 0.f, 0.f, 0.f, 0.f};
        for (int e = beg + slot; e < end; e += 16) {
            int s = esrc[e];
            uint4 u = *(const uint4*)(xb + (size_t)s * DIM + chunk * 8);  // 8 bf16 = 16 B
            acc[0] += __uint_as_float(u.x << 16);
            acc[1] += __uint_as_float(u.x & 0xFFFF0000u);
            acc[2] += __uint_as_float(u.y << 16);
            acc[3] += __uint_as_float(u.y & 0xFFFF0000u);
            acc[4] += __uint_as_float(u.z << 16);
            acc[5] += __uint_as_float(u.z & 0xFFFF0000u);
            acc[6] += __uint_as_float(u.w << 16);
            acc[7] += __uint_as_float(u.w & 0xFFFF0000u);
        }
#pragma unroll
        for (int off = 4; off < 64; off <<= 1) {
#pragma unroll
            for (int i2 = 0; i2 < 8; ++i2)
                acc[i2] += __shfl_xor(acc[i2], off, 64);
        }
        if (slot == 0) {             // lanes 0-3: add self row, publish h (same-wave LDS)
            const float4 s0 = *(const float4*)(x + (size_t)node * DIM + chunk * 8);
            const float4 s1 = *(const float4*)(x + (size_t)node * DIM + chunk * 8 + 4);
            float4 r0 = make_float4(acc[0] + s0.x, acc[1] + s0.y, acc[2] + s0.z, acc[3] + s0.w);
            float4 r1 = make_float4(acc[4] + s1.x, acc[5] + s1.y, acc[6] + s1.z, acc[7] + s1.w);
            *(float4*)(&h[wv][chunk * 8]) = r0;
            *(float4*)(&h[wv][chunk * 8 + 4]) = r1;
        }
        float a = 0.f;
#pragma unroll
        for (int k = 0; k < 16; ++k) {
            int kk = half * 16 + k;
            a += h[wv][kk] * Wb[kk * DIM + col];
        }
        a += __shfl_xor(a, 32, 64);
        a += shb[col];
        float hp = a > 0.f ? a : expm1f(a);
        if (half == 0) {
            xnext[(size_t)node * DIM + col] = hp;
            float hn = __shfl_down(hp, 1, 64);
            if ((col & 1) == 0) {
                unsigned pk = (unsigned)f2bf(hp) | ((unsigned)f2bf(hn) << 16);
                *(unsigned*)(xnextb + (size_t)node * DIM + col) = pk;
            }
        }
    }
}

// ===== lin MLP via MFMA (bf16 h, bf16 W, fp32 accum) + Z + segment-max =====
// Block = 256 thr = 4 waves; wave owns 64 rows = 4 tiles of 16. N % 16 == 0.
// A frag: A[m=lane&15][k=(lane>>4)*8+j]  B frag: B[k=(lane>>4)*8+j][n=lane&15]
// D frag: col=lane&15, row=(lane>>4)*4+reg   [per verified gfx950 layouts]
#define LINM_ROWS_PER_BLOCK 256
template <bool FIRST>
__global__ __launch_bounds__(256) void linZ_kernel(
        const unsigned short* __restrict__ hb,   // [N,32] bf16 bits
        const unsigned short* __restrict__ Wb,   // [32,32] bf16 folded lin W
        const float* __restrict__ shf,           // [32] fp32 shift
        const int* __restrict__ batch,           // [N] sorted
        const float* __restrict__ lw_ptr,
        float* __restrict__ Z,                   // [N,32]
        unsigned* __restrict__ segmax)           // [G,32] encoded
{
    __shared__ unsigned segloc[8 * DIM];
    int t = threadIdx.x;
    if (t < 8 * DIM) segloc[t] = 0;

    int wv = t >> 6, lane = t & 63;
    int m = lane & 15;          // A row within tile / D col
    int kg = lane >> 4;         // k-group 0..3

    short8 b0, b1;
#pragma unroll
    for (int j = 0; j < 8; ++j) {
        int k = kg * 8 + j;
        b0[j] = (short)Wb[k * DIM + m];
        b1[j] = (short)Wb[k * DIM + 16 + m];
    }
    float sh0 = shf[m], sh1 = shf[m + 16];
    float lw = lw_ptr[0];
    int blk0 = blockIdx.x * LINM_ROWS_PER_BLOCK;
    int gfirst = batch[blk0];
    __syncthreads();

    int r0 = blk0 + wv * 64;
    for (int tile = 0; tile < 4; ++tile) {
        int row0 = r0 + tile * 16;
        if (row0 >= N_NODES) break;               // N%16==0: tiles all-or-nothing
        short8 a = *(const short8*)(hb + (size_t)(row0 + m) * DIM + kg * 8);
        f32x4 d0 = {0.f, 0.f, 0.f, 0.f}, d1 = {0.f, 0.f, 0.f, 0.f};
        d0 = __builtin_amdgcn_mfma_f32_16x16x32_bf16(a, b0, d0, 0, 0, 0);
        d1 = __builtin_amdgcn_mfma_f32_16x16x32_bf16(a, b1, d1, 0, 0, 0);
#pragma unroll
        for (int r = 0; r < 4; ++r) {
            int row = row0 + kg * 4 + r;
            float a0 = d0[r] + sh0;
            float a1 = d1[r] + sh1;
            float z0 = a0 > 0.f ? a0 : expm1f(a0);
            float z1 = a1 > 0.f ? a1 : expm1f(a1);
            float zw0 = lw * z0, zw1 = lw * z1;
            size_t zi = (size_t)row * DIM;
            if (FIRST) { Z[zi + m] = zw0; Z[zi + 16 + m] = zw1; }
            else       { Z[zi + m] += zw0; Z[zi + 16 + m] += zw1; }
            float s0 = FIRST ? z0 : zw0, s1 = FIRST ? z1 : zw1;
            int g = batch[row];
            int go = g - gfirst;
            if (go < 8) {
                atomicMax(&segloc[go * DIM + m], enc_f32(s0));
                atomicMax(&segloc[go * DIM + 16 + m], enc_f32(s1));
            } else {
                atomicMax(&segmax[g * DIM + m], enc_f32(s0));
                atomicMax(&segmax[g * DIM + 16 + m], enc_f32(s1));
            }
        }
    }
    __syncthreads();
    if (t < 8 * DIM) {
        unsigned v = segloc[t];
        if (v) atomicMax(&segmax[(gfirst + (t >> 5)) * DIM + (t & 31)], v);
    }
}

// out[g][j] += decode(segmax[g][j]); reset segmax for the next layer's atomics.
__global__ void add_out_kernel(unsigned* __restrict__ segmax, float* __restrict__ out) {
    int t = blockIdx.x * blockDim.x + threadIdx.x;  // 2048
    out[t] += dec_f32(segmax[t]);
    segmax[t] = 0;
}

extern "C" void kernel_launch(void* const* d_in, const int* in_sizes, int n_in,
                              void* d_out, int out_size, void* d_ws, size_t ws_size,
                              hipStream_t stream) {
    const float* x0        = (const float*)d_in[0];
    const int*   ei        = (const int*)d_in[1];     // (2,E): row0=src, row1=dst
    const int*   batch     = (const int*)d_in[2];
    const float* lw        = (const float*)d_in[3];
    const float* lin_W     = (const float*)d_in[4];
    const float* lin_b     = (const float*)d_in[5];
    const float* lin_gamma = (const float*)d_in[6];
    const float* lin_beta  = (const float*)d_in[7];
    const float* lin_mean  = (const float*)d_in[8];
    const float* lin_var   = (const float*)d_in[9];
    const float* conv_W    = (const float*)d_in[10];
    const float* conv_b    = (const float*)d_in[11];
    const float* conv_gamma= (const float*)d_in[12];
    const float* conv_beta = (const float*)d_in[13];
    const float* conv_mean = (const float*)d_in[14];
    const float* conv_var  = (const float*)d_in[15];

    float* out  = (float*)d_out;                 // [G*32]
    float* Z    = out + N_GROUPS * DIM;          // [N*32]
    float* xout = Z + (size_t)N_NODES * DIM;     // [N*32] final x

    char* p = (char*)d_ws;
    float*          xbuf    = (float*)p;          p += (size_t)N_NODES * DIM * sizeof(float);
    unsigned short* x0b     = (unsigned short*)p; p += ((size_t)N_NODES * DIM + 4096) * sizeof(unsigned short);
    unsigned short* xbufb   = (unsigned short*)p; p += ((size_t)N_NODES * DIM + 4096) * sizeof(unsigned short);
    unsigned*       binbuf  = (unsigned*)p;       p += (size_t)N_EDGES * sizeof(unsigned);
    int*            esrc    = (int*)p;            p += (size_t)N_EDGES * sizeof(int);
    int*            nodeptr = (int*)p;            p += (NBINS * BIN_NODES + 1) * sizeof(int);
    int*            blockcnt= (int*)p;            p += (size_t)HIST_BLOCKS * NBINS * sizeof(int);
    int*            bincnt  = (int*)p;            p += NBINS * sizeof(int);
    int*            binoff  = (int*)p;            p += (NBINS + 1) * sizeof(int);
    int*            bincur  = (int*)p;            p += NBINS * sizeof(int);
    unsigned*       segmx   = (unsigned*)p;       p += N_GROUPS * DIM * sizeof(unsigned);
    float*          Wf      = (float*)p;          p += 5 * DIM * DIM * sizeof(float);
    float*          shf     = (float*)p;          p += 5 * DIM * sizeof(float);
    unsigned short* Wfb     = (unsigned short*)p; p += 5 * DIM * DIM * sizeof(unsigned short);

    const int* src = ei;
    const int* dst = ei + N_EDGES;

    const int linZ_blocks = (N_NODES + LINM_ROWS_PER_BLOCK - 1) / LINM_ROWS_PER_BLOCK;  // 391
    const int gc_blocks   = (N_NODES + GC_NODES_PER_BLOCK - 1) / GC_NODES_PER_BLOCK;    // 6250
    const int cvt_blocks  = N_NODES * DIM / 4 / 256;                                    // 3125

    hipMemsetAsync(out, 0, N_GROUPS * DIM * sizeof(float), stream);
    hipMemsetAsync(bincnt, 0, NBINS * sizeof(int), stream);
    hipMemsetAsync(segmx, 0, N_GROUPS * DIM * sizeof(unsigned), stream);
    fold_kernel<<<5, 1024, 0, stream>>>(lin_W, lin_b, lin_gamma, lin_beta, lin_mean, lin_var,
                                        conv_W, conv_b, conv_gamma, conv_beta, conv_mean, conv_var,
                                        Wf, shf, Wfb);

    // ---- CSR build + bf16 copy of x0 ----
    binhist_kernel<<<HIST_BLOCKS, 256, 0, stream>>>(dst, bincnt, blockcnt);
    binscan_kernel<<<1, 1024, 0, stream>>>(bincnt, binoff, bincur);
    binscatter_kernel<<<HIST_BLOCKS, 256, 0, stream>>>(src, dst, bincur, binbuf, blockcnt);
    binsort_kernel<<<NBINS, 256, 0, stream>>>(binbuf, binoff, esrc, nodeptr);
    convert_kernel<<<cvt_blocks, 256, 0, stream>>>(x0, x0b);

    // ---- layer 0 ----
    linZ_kernel<true><<<linZ_blocks, 256, 0, stream>>>(x0b, Wfb, shf, batch, lw, Z, segmx);
    add_out_kernel<<<8, 256, 0, stream>>>(segmx, out);

    // ---- layer 1 ----
    gatherconv_kernel<<<gc_blocks, 256, 0, stream>>>(x0, x0b, esrc, nodeptr,
                                                     Wf + 3 * DIM * DIM, shf + 3 * DIM,
                                                     xbuf, xbufb);
    linZ_kernel<false><<<linZ_blocks, 256, 0, stream>>>(xbufb, Wfb + 1 * DIM * DIM, shf + 1 * DIM,
                                                        batch, lw + 1, Z, segmx);
    add_out_kernel<<<8, 256, 0, stream>>>(segmx, out);

    // ---- layer 2 (x0b reused as xout's bf16 mirror; x0b is dead after gc layer-1) ----
    gatherconv_kernel<<<gc_blocks, 256, 0, stream>>>(xbuf, xbufb, esrc, nodeptr,
                                                     Wf + 4 * DIM * DIM, shf + 4 * DIM,
                                                     xout, x0b);
    linZ_kernel<false><<<linZ_blocks, 256, 0, stream>>>(x0b, Wfb + 2 * DIM * DIM, shf + 2 * DIM,
                                                        batch, lw + 2, Z, segmx);
    add_out_kernel<<<8, 256, 0, stream>>>(segmx, out);
}